// Round 2
// 667.197 us; speedup vs baseline: 1.0200x; 1.0200x over previous
//
#include <hip/hip_runtime.h>

#define HDIM 256            // feature dim, fixed by the reference
#define ROWS_PER_WAVE 128   // rows of x each wave reduces
#define GEMM_ROWS 4         // segment-rows per block in the output GEMM

// ---------------------------------------------------------------------------
// flush helper: one wave's float4 accumulator (cols lane*4..lane*4+3) into
// pooled[segid][:] plus the row count into counts[segid].
// ---------------------------------------------------------------------------
__device__ __forceinline__ void flush_acc(float* __restrict__ pooled,
                                          float* __restrict__ counts,
                                          int segid, int lane,
                                          const float4& acc, int cnt)
{
    float* dst = pooled + (long)segid * HDIM + lane * 4;
    atomicAdd(dst + 0, acc.x);
    atomicAdd(dst + 1, acc.y);
    atomicAdd(dst + 2, acc.z);
    atomicAdd(dst + 3, acc.w);
    if (lane == 0) atomicAdd(&counts[segid], (float)cnt);
}

// ---------------------------------------------------------------------------
// Kernel 1: segment-sum of x rows (sorted seg_ids) -> pooled[B][H], counts[B]
// One wave owns 128 contiguous rows. Chunk seg-ids preloaded into 2 regs/lane
// (2 coalesced loads). Loads are DECOUPLED from segment logic: every 8-row
// group issues all 8 float4 loads up front (8-deep MLP even in boundary
// chunks); the flush logic then consumes preloaded seg ids via __shfl.
// ---------------------------------------------------------------------------
__global__ __launch_bounds__(256) void seg_pool_kernel(
    const float* __restrict__ x, const int* __restrict__ seg,
    float* __restrict__ pooled, float* __restrict__ counts, int N)
{
    const int wave = blockIdx.x * 4 + (threadIdx.x >> 6);
    const int lane = threadIdx.x & 63;

    long r0 = (long)wave * ROWS_PER_WAVE;
    if (r0 >= N) return;
    long r1 = r0 + ROWS_PER_WAVE;
    if (r1 > N) r1 = N;
    const int nrows = (int)(r1 - r0);

    // preload this chunk's seg ids: lane j holds seg[r0+j] and seg[r0+64+j]
    long i0 = r0 + lane;       if (i0 >= N) i0 = N - 1;
    long i1 = r0 + 64 + lane;  if (i1 >= N) i1 = N - 1;
    const int sv0 = seg[i0];
    const int sv1 = seg[i1];
    const int sfirst = __shfl(sv0, 0);
    const int slast  = (nrows <= 64) ? __shfl(sv0, nrows - 1)
                                     : __shfl(sv1, nrows - 1 - 64);

    const float4* xp = (const float4*)x + r0 * 64 + lane;  // row stride = 64 float4

    float4 acc = make_float4(0.f, 0.f, 0.f, 0.f);

    if (sfirst == slast) {
        // whole chunk in one segment: branch-free, 8 loads in flight
        int rr = 0;
        for (; rr + 8 <= nrows; rr += 8) {
            float4 v0 = xp[(rr + 0) * 64];
            float4 v1 = xp[(rr + 1) * 64];
            float4 v2 = xp[(rr + 2) * 64];
            float4 v3 = xp[(rr + 3) * 64];
            float4 v4 = xp[(rr + 4) * 64];
            float4 v5 = xp[(rr + 5) * 64];
            float4 v6 = xp[(rr + 6) * 64];
            float4 v7 = xp[(rr + 7) * 64];
            acc.x += ((v0.x + v1.x) + (v2.x + v3.x)) + ((v4.x + v5.x) + (v6.x + v7.x));
            acc.y += ((v0.y + v1.y) + (v2.y + v3.y)) + ((v4.y + v5.y) + (v6.y + v7.y));
            acc.z += ((v0.z + v1.z) + (v2.z + v3.z)) + ((v4.z + v5.z) + (v6.z + v7.z));
            acc.w += ((v0.w + v1.w) + (v2.w + v3.w)) + ((v4.w + v5.w) + (v6.w + v7.w));
        }
        for (; rr < nrows; ++rr) {
            float4 v = xp[rr * 64];
            acc.x += v.x; acc.y += v.y; acc.z += v.z; acc.w += v.w;
        }
        flush_acc(pooled, counts, sfirst, lane, acc, nrows);
    } else {
        // chunk crosses >=1 boundary. Loads are issued unconditionally 8-deep;
        // only the accumulate/flush step consults seg ids (register shfl).
        int cur = sfirst;
        int cnt = 0;
        int rr  = 0;
        for (; rr + 8 <= nrows; rr += 8) {
            float4 v0 = xp[(rr + 0) * 64];
            float4 v1 = xp[(rr + 1) * 64];
            float4 v2 = xp[(rr + 2) * 64];
            float4 v3 = xp[(rr + 3) * 64];
            float4 v4 = xp[(rr + 4) * 64];
            float4 v5 = xp[(rr + 5) * 64];
            float4 v6 = xp[(rr + 6) * 64];
            float4 v7 = xp[(rr + 7) * 64];
            const int s_a = (rr < 64)     ? __shfl(sv0, rr)     : __shfl(sv1, rr - 64);
            const int s_b = (rr + 7 < 64) ? __shfl(sv0, rr + 7) : __shfl(sv1, rr + 7 - 64);
            if (s_a == cur && s_b == cur) {
                // sorted => all 8 rows in cur: branch-free accumulate
                acc.x += ((v0.x + v1.x) + (v2.x + v3.x)) + ((v4.x + v5.x) + (v6.x + v7.x));
                acc.y += ((v0.y + v1.y) + (v2.y + v3.y)) + ((v4.y + v5.y) + (v6.y + v7.y));
                acc.z += ((v0.z + v1.z) + (v2.z + v3.z)) + ((v4.z + v5.z) + (v6.z + v7.z));
                acc.w += ((v0.w + v1.w) + (v2.w + v3.w)) + ((v4.w + v5.w) + (v6.w + v7.w));
                cnt += 8;
            } else {
                // group contains a boundary: per-row, statically unrolled
                // (no runtime-indexed array -> stays in registers)
#define ROW_STEP(J, VJ)                                                          \
                {                                                                \
                    const int s_j = (rr + (J) < 64) ? __shfl(sv0, rr + (J))      \
                                                    : __shfl(sv1, rr + (J) - 64);\
                    if (s_j != cur) {                                            \
                        flush_acc(pooled, counts, cur, lane, acc, cnt);          \
                        acc = make_float4(0.f, 0.f, 0.f, 0.f);                   \
                        cnt = 0; cur = s_j;                                      \
                    }                                                            \
                    acc.x += VJ.x; acc.y += VJ.y; acc.z += VJ.z; acc.w += VJ.w;  \
                    ++cnt;                                                       \
                }
                ROW_STEP(0, v0) ROW_STEP(1, v1) ROW_STEP(2, v2) ROW_STEP(3, v3)
                ROW_STEP(4, v4) ROW_STEP(5, v5) ROW_STEP(6, v6) ROW_STEP(7, v7)
#undef ROW_STEP
            }
        }
        // tail (< 8 rows; only the final wave of the grid hits this)
        for (; rr < nrows; ++rr) {
            const int s_j = (rr < 64) ? __shfl(sv0, rr) : __shfl(sv1, rr - 64);
            if (s_j != cur) {
                flush_acc(pooled, counts, cur, lane, acc, cnt);
                acc = make_float4(0.f, 0.f, 0.f, 0.f);
                cnt = 0; cur = s_j;
            }
            float4 v = xp[rr * 64];
            acc.x += v.x; acc.y += v.y; acc.z += v.z; acc.w += v.w;
            ++cnt;
        }
        flush_acc(pooled, counts, cur, lane, acc, cnt);
    }
}

// ---------------------------------------------------------------------------
// Kernel 0 (prep): transpose W -> Wt AND zero pooled/counts (fused; removes
// the separate memset dispatch). Grid 8x8, block 256 (32x8 tile threads).
// zero region is (B*H + B) floats, float4-stored, grid-strided.
// ---------------------------------------------------------------------------
__global__ __launch_bounds__(256) void prep_kernel(
    const float* __restrict__ W, float* __restrict__ Wt,
    float4* __restrict__ zero_dst, int zero_count4)
{
    __shared__ float tile[32][33];  // +1 pad: conflict-free transposed read
    const int tx = threadIdx.x & 31;
    const int ty = threadIdx.x >> 5;
    const int bx = blockIdx.x;
    const int by = blockIdx.y;
#pragma unroll
    for (int i = 0; i < 32; i += 8)
        tile[ty + i][tx] = W[(by * 32 + ty + i) * HDIM + bx * 32 + tx];

    // zero pooled+counts while the tile loads settle
    const int gtid = (blockIdx.y * gridDim.x + blockIdx.x) * 256 + threadIdx.x;
    const int nth  = gridDim.x * gridDim.y * 256;
    const float4 z = make_float4(0.f, 0.f, 0.f, 0.f);
    for (int i = gtid; i < zero_count4; i += nth) zero_dst[i] = z;

    __syncthreads();
#pragma unroll
    for (int i = 0; i < 32; i += 8)
        Wt[(bx * 32 + ty + i) * HDIM + by * 32 + tx] = tile[tx][ty + i];
}

// ---------------------------------------------------------------------------
// Kernel 2: out[B][H] = relu(pooled @ W^T + counts*b)
// 4 rows x 256 cols per block, 256 blocks -> every CU busy. pooled rows in
// LDS (float4 broadcast reads), Wt streamed coalesced from L2, k unrolled x4.
// ---------------------------------------------------------------------------
__global__ __launch_bounds__(256) void out_gemm_kernel(
    const float* __restrict__ pooled, const float* __restrict__ Wt,
    const float* __restrict__ bias, const float* __restrict__ counts,
    float* __restrict__ out, int B)
{
    __shared__ float sp[GEMM_ROWS][HDIM];  // 4 KB
    const int col = threadIdx.x;
    const int r0  = blockIdx.x * GEMM_ROWS;
    const int rmax = (B - r0 < GEMM_ROWS) ? (B - r0) : GEMM_ROWS;

    // stage 4 rows (4 KB) with one float4 per thread
    {
        const float4* src = (const float4*)(pooled + (long)r0 * HDIM);
        float4* dst = (float4*)&sp[0][0];
        int lim = rmax * (HDIM / 4);
        dst[col] = (col < lim) ? src[col] : make_float4(0.f, 0.f, 0.f, 0.f);
    }
    __syncthreads();

    float a0 = 0.f, a1 = 0.f, a2 = 0.f, a3 = 0.f;
    for (int k = 0; k < HDIM; k += 4) {
        float w0 = Wt[(long)(k + 0) * HDIM + col];
        float w1 = Wt[(long)(k + 1) * HDIM + col];
        float w2 = Wt[(long)(k + 2) * HDIM + col];
        float w3 = Wt[(long)(k + 3) * HDIM + col];
        float4 s0 = *(const float4*)&sp[0][k];
        float4 s1 = *(const float4*)&sp[1][k];
        float4 s2 = *(const float4*)&sp[2][k];
        float4 s3 = *(const float4*)&sp[3][k];
        a0 = fmaf(s0.x, w0, a0); a0 = fmaf(s0.y, w1, a0); a0 = fmaf(s0.z, w2, a0); a0 = fmaf(s0.w, w3, a0);
        a1 = fmaf(s1.x, w0, a1); a1 = fmaf(s1.y, w1, a1); a1 = fmaf(s1.z, w2, a1); a1 = fmaf(s1.w, w3, a1);
        a2 = fmaf(s2.x, w0, a2); a2 = fmaf(s2.y, w1, a2); a2 = fmaf(s2.z, w2, a2); a2 = fmaf(s2.w, w3, a2);
        a3 = fmaf(s3.x, w0, a3); a3 = fmaf(s3.y, w1, a3); a3 = fmaf(s3.z, w2, a3); a3 = fmaf(s3.w, w3, a3);
    }

    const float bv = bias[col];
    float accs[GEMM_ROWS] = {a0, a1, a2, a3};
    for (int r = 0; r < rmax; ++r) {
        float v = accs[r] + counts[r0 + r] * bv;
        out[(long)(r0 + r) * HDIM + col] = fmaxf(v, 0.f);
    }
}

// ---------------------------------------------------------------------------
// Launch.  ws layout: pooled (B*H f32) | counts (B f32) | Wt (H*H f32)
// ---------------------------------------------------------------------------
extern "C" void kernel_launch(void* const* d_in, const int* in_sizes, int n_in,
                              void* d_out, int out_size, void* d_ws, size_t ws_size,
                              hipStream_t stream)
{
    const float* x   = (const float*)d_in[0];
    const int*   seg = (const int*)d_in[1];
    const float* W   = (const float*)d_in[2];
    const float* b   = (const float*)d_in[3];
    float*       out = (float*)d_out;

    const int N = in_sizes[0] / HDIM;
    const int B = out_size / HDIM;

    float* pooled = (float*)d_ws;
    float* counts = pooled + (size_t)B * HDIM;
    float* Wt     = counts + B;

    // prep: transpose W + zero pooled/counts  (must precede seg_pool; same stream)
    const int zero_count4 = (B * HDIM + B) / 4;   // both divisible by 4
    prep_kernel<<<dim3(HDIM / 32, HDIM / 32), 256, 0, stream>>>(
        W, Wt, (float4*)d_ws, zero_count4);

    // segment pooling: one wave per 128 rows, 4 waves per block
    const int waves  = (N + ROWS_PER_WAVE - 1) / ROWS_PER_WAVE;
    const int blocks = (waves + 3) / 4;
    seg_pool_kernel<<<blocks, 256, 0, stream>>>(x, seg, pooled, counts, N);

    // tiny output GEMM + count*bias + relu
    const int gblocks = (B + GEMM_ROWS - 1) / GEMM_ROWS;
    out_gemm_kernel<<<gblocks, 256, 0, stream>>>(pooled, Wt, b, counts, out, B);
}